// Round 8
// baseline (914.180 us; speedup 1.0000x reference)
//
#include <hip/hip_runtime.h>
#include <math.h>

#define BB 32
#define TT 100
#define VV 10000
#define DD 128
#define OUTN 1000
#define G3 384

// ---------------------------------------------------------------------------
// K1: sparse embedding sum  e[b,t,:] = sum_{v: x!=0} x[b,t,v] * emb[v,:]
// grid = B*T = 3200 blocks (12.5/CU -> HBM-BW-bound scan), 256 threads.
// ---------------------------------------------------------------------------
__global__ __launch_bounds__(256) void k_embed(
    const float* __restrict__ x, const float* __restrict__ emb,
    float* __restrict__ e, int* __restrict__ mask)
{
    const int bt  = blockIdx.x;
    const int tid = threadIdx.x;
    __shared__ int   s_cnt;
    __shared__ int   s_any;
    __shared__ int   s_idx[256];
    __shared__ float s_val[256];
    if (tid == 0) { s_cnt = 0; s_any = 0; }
    __syncthreads();

    const float4* x4 = (const float4*)(x + (size_t)bt * VV);
    for (int i = tid; i < VV / 4; i += 256) {
        float4 v = x4[i];
        if (v.x != 0.f) { int p = atomicAdd(&s_cnt, 1); if (p < 256) { s_idx[p] = 4*i+0; s_val[p] = v.x; } }
        if (v.y != 0.f) { int p = atomicAdd(&s_cnt, 1); if (p < 256) { s_idx[p] = 4*i+1; s_val[p] = v.y; } }
        if (v.z != 0.f) { int p = atomicAdd(&s_cnt, 1); if (p < 256) { s_idx[p] = 4*i+2; s_val[p] = v.z; } }
        if (v.w != 0.f) { int p = atomicAdd(&s_cnt, 1); if (p < 256) { s_idx[p] = 4*i+3; s_val[p] = v.w; } }
    }
    __syncthreads();
    int cnt = s_cnt; if (cnt > 256) cnt = 256;
    if (tid < DD) {
        float a0 = 0.f, a1 = 0.f, a2 = 0.f, a3 = 0.f;
        int i = 0;
        for (; i + 3 < cnt; i += 4) {
            a0 += s_val[i+0] * emb[(size_t)s_idx[i+0] * DD + tid];
            a1 += s_val[i+1] * emb[(size_t)s_idx[i+1] * DD + tid];
            a2 += s_val[i+2] * emb[(size_t)s_idx[i+2] * DD + tid];
            a3 += s_val[i+3] * emb[(size_t)s_idx[i+3] * DD + tid];
        }
        for (; i < cnt; ++i)
            a0 += s_val[i] * emb[(size_t)s_idx[i] * DD + tid];
        float acc = (a0 + a1) + (a2 + a3);
        e[(size_t)bt * DD + tid] = acc;
        if (acc != 0.f) s_any = 1;
    }
    __syncthreads();
    if (tid == 0) mask[bt] = s_any;
}

// ---------------------------------------------------------------------------
// K2: input-side gates
// ---------------------------------------------------------------------------
__global__ __launch_bounds__(256) void k_gates(
    const float* __restrict__ e,
    const float* __restrict__ wih_f, const float* __restrict__ bih_f,
    const float* __restrict__ wih_b, const float* __restrict__ bih_b,
    float* __restrict__ x3)
{
    const int r0  = blockIdx.x * 8;
    const int tid = threadIdx.x;
    __shared__ __align__(16) float se[8][DD];
    for (int i = tid; i < 8 * DD; i += 256)
        se[i >> 7][i & 127] = e[(size_t)(r0 + (i >> 7)) * DD + (i & 127)];
    __syncthreads();

    for (int cc = 0; cc < 3; ++cc) {
        const int col = tid + cc * 256;
        const float* wrow;
        float bias;
        if (col < G3) { wrow = wih_f + (size_t)col * DD;        bias = bih_f[col]; }
        else          { wrow = wih_b + (size_t)(col - G3) * DD; bias = bih_b[col - G3]; }
        float acc[8];
        #pragma unroll
        for (int r = 0; r < 8; ++r) acc[r] = 0.f;
        const float4* w4 = (const float4*)wrow;
        for (int k4 = 0; k4 < DD / 4; ++k4) {
            float4 w = w4[k4];
            #pragma unroll
            for (int r = 0; r < 8; ++r) {
                float4 ev = *(const float4*)&se[r][4 * k4];
                acc[r] += ev.x * w.x + ev.y * w.y + ev.z * w.z + ev.w * w.w;
            }
        }
        #pragma unroll
        for (int r = 0; r < 8; ++r)
            x3[(size_t)(r0 + r) * 768 + col] = acc[r] + bias;
    }
}

// ---------------------------------------------------------------------------
// K3: GRU v8 — batch-paired weight streaming.
// History: v1-v7 all tried to make 96-192 weight floats/thread register-
// resident; the allocator refused every time (VGPR 84/92/116/76/44/68/68 —
// launch-bounds cap was NOT binding, (512,1) changed nothing). Measured
// 744ns/step ~= 86% of the per-CU L1 load-path roofline (196KB/step/CU at
// ~128B/cyc = 640ns). So: stop fighting residency, CUT BYTES PER CU.
// v8: 32 blocks = (dir x 16 batch-pairs); each streamed weight float4 feeds
// TWO batches -> 98KB/step/CU (floor ~768cyc ~= VALU 768cyc, balanced).
// Weights are plain in-loop loads; a volatile-asm pointer launder per
// iteration stops LICM from hoisting (then spilling) them, while leaving
// the loads schedulable for vmcnt interleave.
// Falsifier: gru flat ~74us + flat VALUBusy => DS/issue-bound, not load-bound.
// ---------------------------------------------------------------------------
__global__ __launch_bounds__(512, 1) void k_gru(
    const float* __restrict__ x3,
    const float* __restrict__ whh_f, const float* __restrict__ bhh_f,
    const float* __restrict__ whh_b, const float* __restrict__ bhh_b,
    float* __restrict__ h_all)
{
    const int dir = blockIdx.x & 1;
    const int bp  = blockIdx.x >> 1;       // 0..15
    const int b0  = bp * 2, b1 = b0 + 1;
    const int tid = threadIdx.x;           // 0..511
    const int g   = tid & 127;             // output dim
    const int kq  = tid >> 7;              // k-quarter 0..3
    const int kb  = kq * 32;
    const float* whh = dir ? whh_b : whh_f;
    const float* bhh = dir ? bhh_b : bhh_f;

    const float4* pr4 = (const float4*)(whh + (size_t)(g         ) * DD + kb);
    const float4* pz4 = (const float4*)(whh + (size_t)(DD     + g) * DD + kb);
    const float4* pn4 = (const float4*)(whh + (size_t)(2 * DD + g) * DD + kb);

    float bhr = 0.f, bhz = 0.f, bhn = 0.f;
    if (tid < DD) { bhr = bhh[g]; bhz = bhh[DD + g]; bhn = bhh[2 * DD + g]; }

    __shared__ __align__(16) float h_lds[2][DD];
    __shared__ float p_lds[2][9 * DD];     // [batch][(kq-1)*3 + gate][g]
    float h0 = 0.f, h1 = 0.f;
    if (tid < 2 * DD) h_lds[tid >> 7][tid & 127] = 0.f;

    // prefetch x3 for t=0, both batches (tid<128 finishes both in phase 2)
    float x0r = 0.f, x0z = 0.f, x0n = 0.f, x1r = 0.f, x1z = 0.f, x1n = 0.f;
    {
        const int te0 = dir ? TT - 1 : 0;
        const float* p0 = x3 + (size_t)(b0 * TT + te0) * 768 + dir * G3;
        const float* p1 = x3 + (size_t)(b1 * TT + te0) * 768 + dir * G3;
        if (tid < DD) {
            x0r = p0[g]; x0z = p0[DD + g]; x0n = p0[2 * DD + g];
            x1r = p1[g]; x1z = p1[DD + g]; x1n = p1[2 * DD + g];
        }
    }
    __syncthreads();

#define Q8(M) M(0) M(1) M(2) M(3) M(4) M(5) M(6) M(7)
    for (int t = 0; t < TT; ++t) {
        const int te = dir ? (TT - 1 - t) : t;

        // launder pointers: redefined-by-asm each iteration => LICM cannot
        // hoist the weight loads out of the loop (which would force a spill).
        const float4* pr = pr4; asm volatile("" : "+v"(pr));
        const float4* pz = pz4; asm volatile("" : "+v"(pz));
        const float4* pn = pn4; asm volatile("" : "+v"(pn));

        // stream weights (issued first, consumed under vmcnt interleave)
#define DECLW(i) const float4 wr##i = pr[i]; const float4 wz##i = pz[i]; const float4 wn##i = pn[i];
        Q8(DECLW)
#undef DECLW

        // prefetch x3 for t+1
        float n0r = 0.f, n0z = 0.f, n0n = 0.f, n1r = 0.f, n1z = 0.f, n1n = 0.f;
        if (t + 1 < TT && tid < DD) {
            const int tn = dir ? (TT - 2 - t) : (t + 1);
            const float* q0 = x3 + (size_t)(b0 * TT + tn) * 768 + dir * G3;
            const float* q1 = x3 + (size_t)(b1 * TT + tn) * 768 + dir * G3;
            n0r = q0[g]; n0z = q0[DD + g]; n0n = q0[2 * DD + g];
            n1r = q1[g]; n1z = q1[DD + g]; n1n = q1[2 * DD + g];
        }

        // partial dots: each weight float4 feeds BOTH batches (6 chains)
        float ar0 = 0.f, az0 = 0.f, an0 = 0.f, ar1 = 0.f, az1 = 0.f, an1 = 0.f;
#define FMAB(i) { \
        const float4 u0 = *(const float4*)&h_lds[0][kb + 4 * (i)]; \
        const float4 u1 = *(const float4*)&h_lds[1][kb + 4 * (i)]; \
        ar0 += wr##i.x*u0.x + wr##i.y*u0.y + wr##i.z*u0.z + wr##i.w*u0.w; \
        az0 += wz##i.x*u0.x + wz##i.y*u0.y + wz##i.z*u0.z + wz##i.w*u0.w; \
        an0 += wn##i.x*u0.x + wn##i.y*u0.y + wn##i.z*u0.z + wn##i.w*u0.w; \
        ar1 += wr##i.x*u1.x + wr##i.y*u1.y + wr##i.z*u1.z + wr##i.w*u1.w; \
        az1 += wz##i.x*u1.x + wz##i.y*u1.y + wz##i.z*u1.z + wz##i.w*u1.w; \
        an1 += wn##i.x*u1.x + wn##i.y*u1.y + wn##i.z*u1.z + wn##i.w*u1.w; }
        Q8(FMAB)
#undef FMAB

        if (kq) {
            const int q = (kq - 1) * 3;
            p_lds[0][(q + 0) * DD + g] = ar0;
            p_lds[0][(q + 1) * DD + g] = az0;
            p_lds[0][(q + 2) * DD + g] = an0;
            p_lds[1][(q + 0) * DD + g] = ar1;
            p_lds[1][(q + 1) * DD + g] = az1;
            p_lds[1][(q + 2) * DD + g] = an1;
        }
        __syncthreads();

        if (tid < DD) {
            // batch 0
            {
                float hr = ar0 + p_lds[0][0*DD+g] + p_lds[0][3*DD+g] + p_lds[0][6*DD+g] + bhr;
                float hz = az0 + p_lds[0][1*DD+g] + p_lds[0][4*DD+g] + p_lds[0][7*DD+g] + bhz;
                float hn = an0 + p_lds[0][2*DD+g] + p_lds[0][5*DD+g] + p_lds[0][8*DD+g] + bhn;
                float r  = __builtin_amdgcn_rcpf(1.f + __expf(-(x0r + hr)));
                float z  = __builtin_amdgcn_rcpf(1.f + __expf(-(x0z + hz)));
                float e2 = __expf(2.f * (x0n + r * hn));
                float n  = 1.f - 2.f * __builtin_amdgcn_rcpf(e2 + 1.f);
                float hnew = n + z * (h0 - n);
                h0 = hnew;
                h_lds[0][g] = hnew;
                h_all[(size_t)((dir * BB + b0) * TT + te) * DD + g] = hnew;
            }
            // batch 1
            {
                float hr = ar1 + p_lds[1][0*DD+g] + p_lds[1][3*DD+g] + p_lds[1][6*DD+g] + bhr;
                float hz = az1 + p_lds[1][1*DD+g] + p_lds[1][4*DD+g] + p_lds[1][7*DD+g] + bhz;
                float hn = an1 + p_lds[1][2*DD+g] + p_lds[1][5*DD+g] + p_lds[1][8*DD+g] + bhn;
                float r  = __builtin_amdgcn_rcpf(1.f + __expf(-(x1r + hr)));
                float z  = __builtin_amdgcn_rcpf(1.f + __expf(-(x1z + hz)));
                float e2 = __expf(2.f * (x1n + r * hn));
                float n  = 1.f - 2.f * __builtin_amdgcn_rcpf(e2 + 1.f);
                float hnew = n + z * (h1 - n);
                h1 = hnew;
                h_lds[1][g] = hnew;
                h_all[(size_t)((dir * BB + b1) * TT + te) * DD + g] = hnew;
            }
        }
        __syncthreads();
        x0r = n0r; x0z = n0z; x0n = n0n;
        x1r = n1r; x1z = n1z; x1n = n1n;
    }
#undef Q8
}

// ---------------------------------------------------------------------------
// K4: FUSED attention + h_last + combine + logits. One block per batch.
// ---------------------------------------------------------------------------
__global__ __launch_bounds__(256) void k_attn_logits(
    const float* __restrict__ h_all, const int* __restrict__ mask,
    const float* __restrict__ attn_w, const float* __restrict__ attn_b,
    const float* __restrict__ comb_w, const float* __restrict__ comb_b,
    const float* __restrict__ fc_w, const float* __restrict__ fc_b,
    float* __restrict__ out)
{
    const int b   = blockIdx.x;
    const int tid = threadIdx.x;
    __shared__ float s_aw[256];
    __shared__ float s_sc[128];
    __shared__ int   s_m[128];
    __shared__ float s_red[128];
    __shared__ __align__(16) float s_ch[512];
    __shared__ __align__(16) float s_feat[128];

    s_aw[tid] = attn_w[tid];
    int m = 0;
    if (tid < 128) {
        m = (tid < TT) ? mask[b * TT + tid] : 0;
        s_m[tid] = m;
    }
    __syncthreads();
    for (int s = 64; s > 0; s >>= 1) {
        if (tid < s) s_m[tid] += s_m[tid + s];
        __syncthreads();
    }
    const int last = s_m[0] - 1;

    const float* hf = h_all + (size_t)(0 * BB + b) * TT * DD;
    const float* hb = h_all + (size_t)(1 * BB + b) * TT * DD;

    float sc = -1e9f;
    if (tid < TT) {
        float a = attn_b[0];
        const float4* hf4 = (const float4*)(hf + (size_t)tid * DD);
        const float4* hb4 = (const float4*)(hb + (size_t)tid * DD);
        for (int k = 0; k < DD / 4; ++k) {
            float4 v = hf4[k];
            a += v.x * s_aw[4*k] + v.y * s_aw[4*k+1] + v.z * s_aw[4*k+2] + v.w * s_aw[4*k+3];
        }
        for (int k = 0; k < DD / 4; ++k) {
            float4 v = hb4[k];
            a += v.x * s_aw[DD+4*k] + v.y * s_aw[DD+4*k+1] + v.z * s_aw[DD+4*k+2] + v.w * s_aw[DD+4*k+3];
        }
        sc = m ? a : -1e9f;
    }
    if (tid < 128) { s_sc[tid] = sc; s_red[tid] = sc; }
    __syncthreads();
    for (int s = 64; s > 0; s >>= 1) {
        if (tid < s) s_red[tid] = fmaxf(s_red[tid], s_red[tid + s]);
        __syncthreads();
    }
    const float mx = s_red[0];
    __syncthreads();
    float ex = 0.f;
    if (tid < 128) { ex = __expf(s_sc[tid] - mx); s_sc[tid] = ex; s_red[tid] = ex; }
    __syncthreads();
    for (int s = 64; s > 0; s >>= 1) {
        if (tid < s) s_red[tid] += s_red[tid + s];
        __syncthreads();
    }
    const float inv = 1.f / s_red[0];
    __syncthreads();

    {
        const int fl = tid & 127;
        const float* hp = (tid < 128) ? hf : hb;
        float csum = 0.f;
        for (int t = 0; t < TT; ++t)
            csum += s_sc[t] * hp[(size_t)t * DD + fl];
        s_ch[tid]       = csum * inv;
        s_ch[256 + tid] = hp[(size_t)last * DD + fl];
    }
    __syncthreads();

    if (tid < 128) {
        float a = comb_b[tid];
        const float4* cw = (const float4*)(comb_w + (size_t)tid * 512);
        for (int k = 0; k < 128; ++k) {
            float4 w4 = cw[k];
            float4 v4 = *(const float4*)&s_ch[4 * k];
            a += w4.x * v4.x + w4.y * v4.y + w4.z * v4.z + w4.w * v4.w;
        }
        s_feat[tid] = tanhf(a);
    }
    __syncthreads();

    // logits: 1000 outputs, 4 per thread
    #pragma unroll
    for (int j = 0; j < 4; ++j) {
        const int o = j * 256 + tid;
        if (o < OUTN) {
            float a = fc_b[o];
            const float4* w4 = (const float4*)(fc_w + (size_t)o * DD);
            for (int k = 0; k < DD / 4; ++k) {
                float4 w = w4[k];
                float4 v = *(const float4*)&s_feat[4 * k];
                a += w.x * v.x + w.y * v.y + w.z * v.z + w.w * v.w;
            }
            out[(size_t)b * OUTN + o] = a;
        }
    }
}

// ---------------------------------------------------------------------------
extern "C" void kernel_launch(void* const* d_in, const int* in_sizes, int n_in,
                              void* d_out, int out_size, void* d_ws, size_t ws_size,
                              hipStream_t stream)
{
    const float* x      = (const float*)d_in[0];
    const float* emb    = (const float*)d_in[1];
    const float* wih_f  = (const float*)d_in[2];
    const float* whh_f  = (const float*)d_in[3];
    const float* bih_f  = (const float*)d_in[4];
    const float* bhh_f  = (const float*)d_in[5];
    const float* wih_b  = (const float*)d_in[6];
    const float* whh_b  = (const float*)d_in[7];
    const float* bih_b  = (const float*)d_in[8];
    const float* bhh_b  = (const float*)d_in[9];
    const float* attn_w = (const float*)d_in[10];
    const float* attn_b = (const float*)d_in[11];
    const float* comb_w = (const float*)d_in[12];
    const float* comb_b = (const float*)d_in[13];
    const float* fc_w   = (const float*)d_in[14];
    const float* fc_b   = (const float*)d_in[15];
    float* out = (float*)d_out;

    // workspace layout (floats)
    float* ws    = (float*)d_ws;
    float* e     = ws;                      // 409600
    float* x3    = ws + 409600;             // 2457600
    float* h_all = ws + 2867200;            // 819200
    int*   mask  = (int*)(ws + 3686400);    // 3200      (total ~14.8 MB)

    k_embed       <<<BB * TT,     256, 0, stream>>>(x, emb, e, mask);
    k_gates       <<<(BB * TT)/8, 256, 0, stream>>>(e, wih_f, bih_f, wih_b, bih_b, x3);
    k_gru         <<<BB,          512, 0, stream>>>(x3, whh_f, bhh_f, whh_b, bhh_b, h_all);
    k_attn_logits <<<BB,          256, 0, stream>>>(h_all, mask, attn_w, attn_b, comb_w, comb_b, fc_w, fc_b, out);
}

// Round 10
// 391.016 us; speedup vs baseline: 2.3380x; 2.3380x over previous
//
#include <hip/hip_runtime.h>
#include <math.h>

#define BB 32
#define TT 100
#define VV 10000
#define DD 128
#define OUTN 1000
#define G3 384

// ---------------------------------------------------------------------------
// K1: sparse embedding sum (unchanged R7)
// ---------------------------------------------------------------------------
__global__ __launch_bounds__(256) void k_embed(
    const float* __restrict__ x, const float* __restrict__ emb,
    float* __restrict__ e, int* __restrict__ mask)
{
    const int bt  = blockIdx.x;
    const int tid = threadIdx.x;
    __shared__ int   s_cnt;
    __shared__ int   s_any;
    __shared__ int   s_idx[256];
    __shared__ float s_val[256];
    if (tid == 0) { s_cnt = 0; s_any = 0; }
    __syncthreads();

    const float4* x4 = (const float4*)(x + (size_t)bt * VV);
    for (int i = tid; i < VV / 4; i += 256) {
        float4 v = x4[i];
        if (v.x != 0.f) { int p = atomicAdd(&s_cnt, 1); if (p < 256) { s_idx[p] = 4*i+0; s_val[p] = v.x; } }
        if (v.y != 0.f) { int p = atomicAdd(&s_cnt, 1); if (p < 256) { s_idx[p] = 4*i+1; s_val[p] = v.y; } }
        if (v.z != 0.f) { int p = atomicAdd(&s_cnt, 1); if (p < 256) { s_idx[p] = 4*i+2; s_val[p] = v.z; } }
        if (v.w != 0.f) { int p = atomicAdd(&s_cnt, 1); if (p < 256) { s_idx[p] = 4*i+3; s_val[p] = v.w; } }
    }
    __syncthreads();
    int cnt = s_cnt; if (cnt > 256) cnt = 256;
    if (tid < DD) {
        float a0 = 0.f, a1 = 0.f, a2 = 0.f, a3 = 0.f;
        int i = 0;
        for (; i + 3 < cnt; i += 4) {
            a0 += s_val[i+0] * emb[(size_t)s_idx[i+0] * DD + tid];
            a1 += s_val[i+1] * emb[(size_t)s_idx[i+1] * DD + tid];
            a2 += s_val[i+2] * emb[(size_t)s_idx[i+2] * DD + tid];
            a3 += s_val[i+3] * emb[(size_t)s_idx[i+3] * DD + tid];
        }
        for (; i < cnt; ++i)
            a0 += s_val[i] * emb[(size_t)s_idx[i] * DD + tid];
        float acc = (a0 + a1) + (a2 + a3);
        e[(size_t)bt * DD + tid] = acc;
        if (acc != 0.f) s_any = 1;
    }
    __syncthreads();
    if (tid == 0) mask[bt] = s_any;
}

// ---------------------------------------------------------------------------
// K2: input-side gates (unchanged R7)
// ---------------------------------------------------------------------------
__global__ __launch_bounds__(256) void k_gates(
    const float* __restrict__ e,
    const float* __restrict__ wih_f, const float* __restrict__ bih_f,
    const float* __restrict__ wih_b, const float* __restrict__ bih_b,
    float* __restrict__ x3)
{
    const int r0  = blockIdx.x * 8;
    const int tid = threadIdx.x;
    __shared__ __align__(16) float se[8][DD];
    for (int i = tid; i < 8 * DD; i += 256)
        se[i >> 7][i & 127] = e[(size_t)(r0 + (i >> 7)) * DD + (i & 127)];
    __syncthreads();

    for (int cc = 0; cc < 3; ++cc) {
        const int col = tid + cc * 256;
        const float* wrow;
        float bias;
        if (col < G3) { wrow = wih_f + (size_t)col * DD;        bias = bih_f[col]; }
        else          { wrow = wih_b + (size_t)(col - G3) * DD; bias = bih_b[col - G3]; }
        float acc[8];
        #pragma unroll
        for (int r = 0; r < 8; ++r) acc[r] = 0.f;
        const float4* w4 = (const float4*)wrow;
        for (int k4 = 0; k4 < DD / 4; ++k4) {
            float4 w = w4[k4];
            #pragma unroll
            for (int r = 0; r < 8; ++r) {
                float4 ev = *(const float4*)&se[r][4 * k4];
                acc[r] += ev.x * w.x + ev.y * w.y + ev.z * w.z + ev.w * w.w;
            }
        }
        #pragma unroll
        for (int r = 0; r < 8; ++r)
            x3[(size_t)(r0 + r) * 768 + col] = acc[r] + bias;
    }
}

// ---------------------------------------------------------------------------
// K3: GRU v10 — weights in VIRTUAL AGPR-class registers (compiler-managed).
// v9 (hard-coded physical a0..a95) likely faulted the GPU (container died
// twice): registers outside the kernel's allocation. v10 uses "=a"/"a"
// constraints so the ALLOCATOR assigns AGPRs — guaranteed-legal allocation,
// and the values are still asm-volatile-defined => neither rematerializable
// nor hoistable (the failure modes of v1-v7: VGPR 84/92/116/76/44/68/68).
// AGPR spill needs a VGPR round-trip (expensive in the cost model) and AGPR
// pressure is 96 of ~256 free => no spill reason. In-loop re-read is a 1-cyc
// v_accvgpr_read. Step model: max(VALU ~800cy incl. reads, DS ~770cy) + tail
// => ~45-58us vs v7's 74. Falsifier: reg count <=100 + dur ~74 => backend
// spilled AGPRs too => GRU is floored at the L2-stream roofline; revert v7.
// ---------------------------------------------------------------------------
#define AWR(dst, src) asm volatile("v_accvgpr_write_b32 %0, %1" : "=a"(dst) : "v"(src));
#define ARD(dst, src) asm volatile("v_accvgpr_read_b32 %0, %1" : "=v"(dst) : "a"(src));

#define Q8(M) M(0) M(1) M(2) M(3) M(4) M(5) M(6) M(7)
// 12 AGPR-resident floats per k-slice i: r(4), z(4), n(4)
#define WVARS(i) float Ar0##i, Ar1##i, Ar2##i, Ar3##i, \
                       Az0##i, Az1##i, Az2##i, Az3##i, \
                       An0##i, An1##i, An2##i, An3##i;
#define PRE(i) { float4 w; \
    w = pr4[i]; AWR(Ar0##i, w.x) AWR(Ar1##i, w.y) AWR(Ar2##i, w.z) AWR(Ar3##i, w.w) \
    w = pz4[i]; AWR(Az0##i, w.x) AWR(Az1##i, w.y) AWR(Az2##i, w.z) AWR(Az3##i, w.w) \
    w = pn4[i]; AWR(An0##i, w.x) AWR(An1##i, w.y) AWR(An2##i, w.z) AWR(An3##i, w.w) }
#define STEP(i) { const float4 hv = *(const float4*)&h_lds[kb + 4 * (i)]; \
    float w0, w1, w2, w3; \
    ARD(w0, Ar0##i) ARD(w1, Ar1##i) ARD(w2, Ar2##i) ARD(w3, Ar3##i) \
    (((i)&1) ? ar1 : ar0) += w0*hv.x + w1*hv.y + w2*hv.z + w3*hv.w; \
    ARD(w0, Az0##i) ARD(w1, Az1##i) ARD(w2, Az2##i) ARD(w3, Az3##i) \
    (((i)&1) ? az1 : az0) += w0*hv.x + w1*hv.y + w2*hv.z + w3*hv.w; \
    ARD(w0, An0##i) ARD(w1, An1##i) ARD(w2, An2##i) ARD(w3, An3##i) \
    (((i)&1) ? an1 : an0) += w0*hv.x + w1*hv.y + w2*hv.z + w3*hv.w; }

__global__ __launch_bounds__(512, 1) void k_gru(
    const float* __restrict__ x3,
    const float* __restrict__ whh_f, const float* __restrict__ bhh_f,
    const float* __restrict__ whh_b, const float* __restrict__ bhh_b,
    float* __restrict__ h_all)
{
    const int dir = blockIdx.x & 1;
    const int b   = blockIdx.x >> 1;
    const int tid = threadIdx.x;       // 0..511
    const int g   = tid & 127;         // output dim
    const int kq  = tid >> 7;          // k-quarter: 0..3
    const int kb  = kq * 32;           // k base
    const float* whh = dir ? whh_b : whh_f;
    const float* bhh = dir ? bhh_b : bhh_f;

    const float4* pr4 = (const float4*)(whh + (size_t)(g         ) * DD + kb);
    const float4* pz4 = (const float4*)(whh + (size_t)(DD     + g) * DD + kb);
    const float4* pn4 = (const float4*)(whh + (size_t)(2 * DD + g) * DD + kb);

    Q8(WVARS)
    Q8(PRE)

    float bhr = 0.f, bhz = 0.f, bhn = 0.f;
    if (tid < DD) { bhr = bhh[g]; bhz = bhh[DD + g]; bhn = bhh[2 * DD + g]; }

    __shared__ __align__(16) float h_lds[DD];
    __shared__ float p_lds[9 * DD];    // [(kq-1)*3 + gate][g]
    float h_reg = 0.f;
    if (tid < DD) h_lds[tid] = 0.f;

    // prefetch x3 for t=0
    float xr = 0.f, xz = 0.f, xn = 0.f;
    {
        const float* x3p = x3 + (size_t)(b * TT + (dir ? TT - 1 : 0)) * 768 + dir * G3;
        if (tid < DD) { xr = x3p[g]; xz = x3p[DD + g]; xn = x3p[2 * DD + g]; }
    }
    __syncthreads();

    for (int t = 0; t < TT; ++t) {
        const int te = dir ? (TT - 1 - t) : t;

        // prefetch x3 for t+1
        float nxr = 0.f, nxz = 0.f, nxn = 0.f;
        if (t + 1 < TT) {
            const int tn = dir ? (TT - 2 - t) : (t + 1);
            const float* x3n = x3 + (size_t)(b * TT + tn) * 768 + dir * G3;
            if (tid < DD) { nxr = x3n[g]; nxz = x3n[DD + g]; nxn = x3n[2 * DD + g]; }
        }

        float ar0 = 0.f, ar1 = 0.f, az0 = 0.f, az1 = 0.f, an0 = 0.f, an1 = 0.f;
        Q8(STEP)
        const float pr = ar0 + ar1, pz = az0 + az1, pn = an0 + an1;

        if (kq) {
            const int q = (kq - 1) * 3;
            p_lds[(q + 0) * DD + g] = pr;
            p_lds[(q + 1) * DD + g] = pz;
            p_lds[(q + 2) * DD + g] = pn;
        }
        __syncthreads();

        if (tid < DD) {
            float hr = pr + p_lds[0*DD+g] + p_lds[3*DD+g] + p_lds[6*DD+g] + bhr;
            float hz = pz + p_lds[1*DD+g] + p_lds[4*DD+g] + p_lds[7*DD+g] + bhz;
            float hn = pn + p_lds[2*DD+g] + p_lds[5*DD+g] + p_lds[8*DD+g] + bhn;
            float r  = __builtin_amdgcn_rcpf(1.f + __expf(-(xr + hr)));
            float z  = __builtin_amdgcn_rcpf(1.f + __expf(-(xz + hz)));
            // tanh(x) = 1 - 2/(e^(2x)+1): safe at +/-inf
            float e2 = __expf(2.f * (xn + r * hn));
            float n  = 1.f - 2.f * __builtin_amdgcn_rcpf(e2 + 1.f);
            float hnew = n + z * (h_reg - n);            // == (1-z)*n + z*h
            h_reg = hnew;
            h_lds[g] = hnew;
            h_all[(size_t)((dir * BB + b) * TT + te) * DD + g] = hnew;
        }
        __syncthreads();
        xr = nxr; xz = nxz; xn = nxn;
    }
}

// ---------------------------------------------------------------------------
// K4: FUSED attention + h_last + combine + logits (unchanged R7)
// ---------------------------------------------------------------------------
__global__ __launch_bounds__(256) void k_attn_logits(
    const float* __restrict__ h_all, const int* __restrict__ mask,
    const float* __restrict__ attn_w, const float* __restrict__ attn_b,
    const float* __restrict__ comb_w, const float* __restrict__ comb_b,
    const float* __restrict__ fc_w, const float* __restrict__ fc_b,
    float* __restrict__ out)
{
    const int b   = blockIdx.x;
    const int tid = threadIdx.x;
    __shared__ float s_aw[256];
    __shared__ float s_sc[128];
    __shared__ int   s_m[128];
    __shared__ float s_red[128];
    __shared__ __align__(16) float s_ch[512];
    __shared__ __align__(16) float s_feat[128];

    s_aw[tid] = attn_w[tid];
    int m = 0;
    if (tid < 128) {
        m = (tid < TT) ? mask[b * TT + tid] : 0;
        s_m[tid] = m;
    }
    __syncthreads();
    for (int s = 64; s > 0; s >>= 1) {
        if (tid < s) s_m[tid] += s_m[tid + s];
        __syncthreads();
    }
    const int last = s_m[0] - 1;

    const float* hf = h_all + (size_t)(0 * BB + b) * TT * DD;
    const float* hb = h_all + (size_t)(1 * BB + b) * TT * DD;

    float sc = -1e9f;
    if (tid < TT) {
        float a = attn_b[0];
        const float4* hf4 = (const float4*)(hf + (size_t)tid * DD);
        const float4* hb4 = (const float4*)(hb + (size_t)tid * DD);
        for (int k = 0; k < DD / 4; ++k) {
            float4 v = hf4[k];
            a += v.x * s_aw[4*k] + v.y * s_aw[4*k+1] + v.z * s_aw[4*k+2] + v.w * s_aw[4*k+3];
        }
        for (int k = 0; k < DD / 4; ++k) {
            float4 v = hb4[k];
            a += v.x * s_aw[DD+4*k] + v.y * s_aw[DD+4*k+1] + v.z * s_aw[DD+4*k+2] + v.w * s_aw[DD+4*k+3];
        }
        sc = m ? a : -1e9f;
    }
    if (tid < 128) { s_sc[tid] = sc; s_red[tid] = sc; }
    __syncthreads();
    for (int s = 64; s > 0; s >>= 1) {
        if (tid < s) s_red[tid] = fmaxf(s_red[tid], s_red[tid + s]);
        __syncthreads();
    }
    const float mx = s_red[0];
    __syncthreads();
    float ex = 0.f;
    if (tid < 128) { ex = __expf(s_sc[tid] - mx); s_sc[tid] = ex; s_red[tid] = ex; }
    __syncthreads();
    for (int s = 64; s > 0; s >>= 1) {
        if (tid < s) s_red[tid] += s_red[tid + s];
        __syncthreads();
    }
    const float inv = 1.f / s_red[0];
    __syncthreads();

    {
        const int fl = tid & 127;
        const float* hp = (tid < 128) ? hf : hb;
        float csum = 0.f;
        for (int t = 0; t < TT; ++t)
            csum += s_sc[t] * hp[(size_t)t * DD + fl];
        s_ch[tid]       = csum * inv;
        s_ch[256 + tid] = hp[(size_t)last * DD + fl];
    }
    __syncthreads();

    if (tid < 128) {
        float a = comb_b[tid];
        const float4* cw = (const float4*)(comb_w + (size_t)tid * 512);
        for (int k = 0; k < 128; ++k) {
            float4 w4 = cw[k];
            float4 v4 = *(const float4*)&s_ch[4 * k];
            a += w4.x * v4.x + w4.y * v4.y + w4.z * v4.z + w4.w * v4.w;
        }
        s_feat[tid] = tanhf(a);
    }
    __syncthreads();

    #pragma unroll
    for (int j = 0; j < 4; ++j) {
        const int o = j * 256 + tid;
        if (o < OUTN) {
            float a = fc_b[o];
            const float4* w4 = (const float4*)(fc_w + (size_t)o * DD);
            for (int k = 0; k < DD / 4; ++k) {
                float4 w = w4[k];
                float4 v = *(const float4*)&s_feat[4 * k];
                a += w.x * v.x + w.y * v.y + w.z * v.z + w.w * v.w;
            }
            out[(size_t)b * OUTN + o] = a;
        }
    }
}

// ---------------------------------------------------------------------------
extern "C" void kernel_launch(void* const* d_in, const int* in_sizes, int n_in,
                              void* d_out, int out_size, void* d_ws, size_t ws_size,
                              hipStream_t stream)
{
    const float* x      = (const float*)d_in[0];
    const float* emb    = (const float*)d_in[1];
    const float* wih_f  = (const float*)d_in[2];
    const float* whh_f  = (const float*)d_in[3];
    const float* bih_f  = (const float*)d_in[4];
    const float* bhh_f  = (const float*)d_in[5];
    const float* wih_b  = (const float*)d_in[6];
    const float* whh_b  = (const float*)d_in[7];
    const float* bih_b  = (const float*)d_in[8];
    const float* bhh_b  = (const float*)d_in[9];
    const float* attn_w = (const float*)d_in[10];
    const float* attn_b = (const float*)d_in[11];
    const float* comb_w = (const float*)d_in[12];
    const float* comb_b = (const float*)d_in[13];
    const float* fc_w   = (const float*)d_in[14];
    const float* fc_b   = (const float*)d_in[15];
    float* out = (float*)d_out;

    // workspace layout (floats)
    float* ws    = (float*)d_ws;
    float* e     = ws;                      // 409600
    float* x3    = ws + 409600;             // 2457600
    float* h_all = ws + 2867200;            // 819200
    int*   mask  = (int*)(ws + 3686400);    // 3200      (total ~14.8 MB)

    k_embed       <<<BB * TT,     256, 0, stream>>>(x, emb, e, mask);
    k_gates       <<<(BB * TT)/8, 256, 0, stream>>>(e, wih_f, bih_f, wih_b, bih_b, x3);
    k_gru         <<<2 * BB,      512, 0, stream>>>(x3, whh_f, bhh_f, whh_b, bhh_b, h_all);
    k_attn_logits <<<BB,          256, 0, stream>>>(h_all, mask, attn_w, attn_b, comb_w, comb_b, fc_w, fc_b, out);
}

// Round 11
// 353.677 us; speedup vs baseline: 2.5848x; 1.1056x over previous
//
#include <hip/hip_runtime.h>
#include <math.h>

#define BB 32
#define TT 100
#define VV 10000
#define DD 128
#define OUTN 1000
#define G3 384

// ---------------------------------------------------------------------------
// K1: sparse embedding sum  e[b,t,:] = sum_{v: x!=0} x[b,t,v] * emb[v,:]
// grid = B*T = 3200 blocks (scan is HBM-BW-bound; R6 proved 400 blocks kills
// it: 679 GB/s). Gather unrolled x4 (4 independent load->FMA chains).
// Mandatory-read floor: 128 MB / 6.3 TB/s ~= 20 us.
// ---------------------------------------------------------------------------
__global__ __launch_bounds__(256) void k_embed(
    const float* __restrict__ x, const float* __restrict__ emb,
    float* __restrict__ e, int* __restrict__ mask)
{
    const int bt  = blockIdx.x;
    const int tid = threadIdx.x;
    __shared__ int   s_cnt;
    __shared__ int   s_any;
    __shared__ int   s_idx[256];
    __shared__ float s_val[256];
    if (tid == 0) { s_cnt = 0; s_any = 0; }
    __syncthreads();

    const float4* x4 = (const float4*)(x + (size_t)bt * VV);
    for (int i = tid; i < VV / 4; i += 256) {
        float4 v = x4[i];
        if (v.x != 0.f) { int p = atomicAdd(&s_cnt, 1); if (p < 256) { s_idx[p] = 4*i+0; s_val[p] = v.x; } }
        if (v.y != 0.f) { int p = atomicAdd(&s_cnt, 1); if (p < 256) { s_idx[p] = 4*i+1; s_val[p] = v.y; } }
        if (v.z != 0.f) { int p = atomicAdd(&s_cnt, 1); if (p < 256) { s_idx[p] = 4*i+2; s_val[p] = v.z; } }
        if (v.w != 0.f) { int p = atomicAdd(&s_cnt, 1); if (p < 256) { s_idx[p] = 4*i+3; s_val[p] = v.w; } }
    }
    __syncthreads();
    int cnt = s_cnt; if (cnt > 256) cnt = 256;
    if (tid < DD) {
        float a0 = 0.f, a1 = 0.f, a2 = 0.f, a3 = 0.f;
        int i = 0;
        for (; i + 3 < cnt; i += 4) {
            a0 += s_val[i+0] * emb[(size_t)s_idx[i+0] * DD + tid];
            a1 += s_val[i+1] * emb[(size_t)s_idx[i+1] * DD + tid];
            a2 += s_val[i+2] * emb[(size_t)s_idx[i+2] * DD + tid];
            a3 += s_val[i+3] * emb[(size_t)s_idx[i+3] * DD + tid];
        }
        for (; i < cnt; ++i)
            a0 += s_val[i] * emb[(size_t)s_idx[i] * DD + tid];
        float acc = (a0 + a1) + (a2 + a3);
        e[(size_t)bt * DD + tid] = acc;
        if (acc != 0.f) s_any = 1;
    }
    __syncthreads();
    if (tid == 0) mask[bt] = s_any;
}

// ---------------------------------------------------------------------------
// K2: input-side gates (proven shape, ~7us estimate; never in top-5)
// ---------------------------------------------------------------------------
__global__ __launch_bounds__(256) void k_gates(
    const float* __restrict__ e,
    const float* __restrict__ wih_f, const float* __restrict__ bih_f,
    const float* __restrict__ wih_b, const float* __restrict__ bih_b,
    float* __restrict__ x3)
{
    const int r0  = blockIdx.x * 8;
    const int tid = threadIdx.x;
    __shared__ __align__(16) float se[8][DD];
    for (int i = tid; i < 8 * DD; i += 256)
        se[i >> 7][i & 127] = e[(size_t)(r0 + (i >> 7)) * DD + (i & 127)];
    __syncthreads();

    for (int cc = 0; cc < 3; ++cc) {
        const int col = tid + cc * 256;
        const float* wrow;
        float bias;
        if (col < G3) { wrow = wih_f + (size_t)col * DD;        bias = bih_f[col]; }
        else          { wrow = wih_b + (size_t)(col - G3) * DD; bias = bih_b[col - G3]; }
        float acc[8];
        #pragma unroll
        for (int r = 0; r < 8; ++r) acc[r] = 0.f;
        const float4* w4 = (const float4*)wrow;
        for (int k4 = 0; k4 < DD / 4; ++k4) {
            float4 w = w4[k4];
            #pragma unroll
            for (int r = 0; r < 8; ++r) {
                float4 ev = *(const float4*)&se[r][4 * k4];
                acc[r] += ev.x * w.x + ev.y * w.y + ev.z * w.z + ev.w * w.w;
            }
        }
        #pragma unroll
        for (int r = 0; r < 8; ++r)
            x3[(size_t)(r0 + r) * 768 + col] = acc[r] + bias;
    }
}

// ---------------------------------------------------------------------------
// asm global load: asm-defined => not rematerializable. Final GRU form.
// ---------------------------------------------------------------------------
__device__ __forceinline__ float4 ld_pin_b128(const float4* p)
{
    float4 r;
    asm volatile("global_load_dwordx4 %0, %1, off" : "=v"(r) : "v"(p));
    return r;
}

// ---------------------------------------------------------------------------
// K3: GRU v7 — FINAL. 512 thr = (g 0..127) x (kq 0..3), 64 blocks (1/CU).
// Session verdict after 10 variants: the 96 weight floats/thread CANNOT be
// made register-resident by this compiler (scratch/remat/spill under every
// mechanism: arrays, named scalars, asm pins, volatile pins, launch-bounds
// lifts, physical AGPRs [GPU fault], virtual AGPRs [104us]). Step time is
// therefore set by streaming 196KB/block/step through the L1 return path:
// floor ~1536cyc; v7 measures 1786cyc (86%). Batch-pairing doesn't help
// (per-BLOCK bytes invariant); cross-block splits need per-step global sync;
// LDS-resident weights hit the same 128B/cyc port. This is the floor.
// ---------------------------------------------------------------------------
__global__ __launch_bounds__(512, 1) void k_gru(
    const float* __restrict__ x3,
    const float* __restrict__ whh_f, const float* __restrict__ bhh_f,
    const float* __restrict__ whh_b, const float* __restrict__ bhh_b,
    float* __restrict__ h_all)
{
    const int dir = blockIdx.x & 1;
    const int b   = blockIdx.x >> 1;
    const int tid = threadIdx.x;       // 0..511
    const int g   = tid & 127;         // output dim
    const int kq  = tid >> 7;          // k-quarter: 0..3
    const int kb  = kq * 32;           // k base
    const float* whh = dir ? whh_b : whh_f;
    const float* bhh = dir ? bhh_b : bhh_f;

    const float4* pr4 = (const float4*)(whh + (size_t)(g         ) * DD + kb);
    const float4* pz4 = (const float4*)(whh + (size_t)(DD     + g) * DD + kb);
    const float4* pn4 = (const float4*)(whh + (size_t)(2 * DD + g) * DD + kb);

#define Q8(M) M(0) M(1) M(2) M(3) M(4) M(5) M(6) M(7)
#define DECLW(i) float4 wr##i = ld_pin_b128(pr4 + (i)); \
                 float4 wz##i = ld_pin_b128(pz4 + (i)); \
                 float4 wn##i = ld_pin_b128(pn4 + (i));
    Q8(DECLW)
#undef DECLW
    asm volatile("s_waitcnt vmcnt(0)" ::: "memory");
    __builtin_amdgcn_sched_barrier(0);

    float bhr = 0.f, bhz = 0.f, bhn = 0.f;
    if (tid < DD) { bhr = bhh[g]; bhz = bhh[DD + g]; bhn = bhh[2 * DD + g]; }

    __shared__ __align__(16) float h_lds[DD];
    __shared__ float p_lds[9 * DD];    // [(kq-1)*3 + gate][g]
    float h_reg = 0.f;
    if (tid < DD) h_lds[tid] = 0.f;

    // prefetch x3 for t=0
    float xr = 0.f, xz = 0.f, xn = 0.f;
    {
        const float* x3p = x3 + (size_t)(b * TT + (dir ? TT - 1 : 0)) * 768 + dir * G3;
        if (tid < DD) { xr = x3p[g]; xz = x3p[DD + g]; xn = x3p[2 * DD + g]; }
    }
    __syncthreads();

    for (int t = 0; t < TT; ++t) {
        const int te = dir ? (TT - 1 - t) : t;

        // prefetch x3 for t+1 (hidden under this step's dot + barriers)
        float nxr = 0.f, nxz = 0.f, nxn = 0.f;
        if (t + 1 < TT) {
            const int tn = dir ? (TT - 2 - t) : (t + 1);
            const float* x3n = x3 + (size_t)(b * TT + tn) * 768 + dir * G3;
            if (tid < DD) { nxr = x3n[g]; nxz = x3n[DD + g]; nxn = x3n[2 * DD + g]; }
        }

        // partial dots over this thread's k-quarter; 6 independent chains
        float ar0 = 0.f, ar1 = 0.f, az0 = 0.f, az1 = 0.f, an0 = 0.f, an1 = 0.f;
#define FMA(i) { float4 hv = *(const float4*)&h_lds[kb + 4 * (i)]; \
        (((i)&1) ? ar1 : ar0) += wr##i.x*hv.x + wr##i.y*hv.y + wr##i.z*hv.z + wr##i.w*hv.w; \
        (((i)&1) ? az1 : az0) += wz##i.x*hv.x + wz##i.y*hv.y + wz##i.z*hv.z + wz##i.w*hv.w; \
        (((i)&1) ? an1 : an0) += wn##i.x*hv.x + wn##i.y*hv.y + wn##i.z*hv.z + wn##i.w*hv.w; }
        Q8(FMA)
#undef FMA
        const float pr = ar0 + ar1, pz = az0 + az1, pn = an0 + an1;

        if (kq) {
            const int q = (kq - 1) * 3;
            p_lds[(q + 0) * DD + g] = pr;
            p_lds[(q + 1) * DD + g] = pz;
            p_lds[(q + 2) * DD + g] = pn;
        }
        __syncthreads();

        if (tid < DD) {
            float hr = pr + p_lds[0*DD+g] + p_lds[3*DD+g] + p_lds[6*DD+g] + bhr;
            float hz = pz + p_lds[1*DD+g] + p_lds[4*DD+g] + p_lds[7*DD+g] + bhz;
            float hn = pn + p_lds[2*DD+g] + p_lds[5*DD+g] + p_lds[8*DD+g] + bhn;
            float r  = __builtin_amdgcn_rcpf(1.f + __expf(-(xr + hr)));
            float z  = __builtin_amdgcn_rcpf(1.f + __expf(-(xz + hz)));
            // tanh(x) = 1 - 2/(e^(2x)+1): safe at +/-inf
            float e2 = __expf(2.f * (xn + r * hn));
            float n  = 1.f - 2.f * __builtin_amdgcn_rcpf(e2 + 1.f);
            float hnew = n + z * (h_reg - n);            // == (1-z)*n + z*h
            h_reg = hnew;
            h_lds[g] = hnew;
            h_all[(size_t)((dir * BB + b) * TT + te) * DD + g] = hnew;
        }
        __syncthreads();
        xr = nxr; xz = nxz; xn = nxn;
    }
#undef Q8
}

// ---------------------------------------------------------------------------
// K4a: per-batch attention + h_last + combine -> feat[b,128]
// (separate from logits: the 5-kernel split measured best — R3 351.5 /
//  R5 354.5 vs fused-4-kernel R7 362; the 128-block k_logits spreads the
//  fc_w GEMV far better than a 32-block fused tail.)
// ---------------------------------------------------------------------------
__global__ __launch_bounds__(256) void k_attn(
    const float* __restrict__ h_all, const int* __restrict__ mask,
    const float* __restrict__ attn_w, const float* __restrict__ attn_b,
    const float* __restrict__ comb_w, const float* __restrict__ comb_b,
    float* __restrict__ feat)
{
    const int b   = blockIdx.x;
    const int tid = threadIdx.x;
    __shared__ float s_aw[256];
    __shared__ float s_sc[128];
    __shared__ int   s_m[128];
    __shared__ float s_red[128];
    __shared__ __align__(16) float s_ch[512];

    s_aw[tid] = attn_w[tid];
    int m = 0;
    if (tid < 128) {
        m = (tid < TT) ? mask[b * TT + tid] : 0;
        s_m[tid] = m;
    }
    __syncthreads();
    for (int s = 64; s > 0; s >>= 1) {
        if (tid < s) s_m[tid] += s_m[tid + s];
        __syncthreads();
    }
    const int last = s_m[0] - 1;

    const float* hf = h_all + (size_t)(0 * BB + b) * TT * DD;
    const float* hb = h_all + (size_t)(1 * BB + b) * TT * DD;

    float sc = -1e9f;
    if (tid < TT) {
        float a = attn_b[0];
        const float4* hf4 = (const float4*)(hf + (size_t)tid * DD);
        const float4* hb4 = (const float4*)(hb + (size_t)tid * DD);
        for (int k = 0; k < DD / 4; ++k) {
            float4 v = hf4[k];
            a += v.x * s_aw[4*k] + v.y * s_aw[4*k+1] + v.z * s_aw[4*k+2] + v.w * s_aw[4*k+3];
        }
        for (int k = 0; k < DD / 4; ++k) {
            float4 v = hb4[k];
            a += v.x * s_aw[DD+4*k] + v.y * s_aw[DD+4*k+1] + v.z * s_aw[DD+4*k+2] + v.w * s_aw[DD+4*k+3];
        }
        sc = m ? a : -1e9f;
    }
    if (tid < 128) { s_sc[tid] = sc; s_red[tid] = sc; }
    __syncthreads();
    for (int s = 64; s > 0; s >>= 1) {
        if (tid < s) s_red[tid] = fmaxf(s_red[tid], s_red[tid + s]);
        __syncthreads();
    }
    const float mx = s_red[0];
    __syncthreads();
    float ex = 0.f;
    if (tid < 128) { ex = __expf(s_sc[tid] - mx); s_sc[tid] = ex; s_red[tid] = ex; }
    __syncthreads();
    for (int s = 64; s > 0; s >>= 1) {
        if (tid < s) s_red[tid] += s_red[tid + s];
        __syncthreads();
    }
    const float inv = 1.f / s_red[0];
    __syncthreads();

    {
        const int fl = tid & 127;
        const float* hp = (tid < 128) ? hf : hb;
        float csum = 0.f;
        for (int t = 0; t < TT; ++t)
            csum += s_sc[t] * hp[(size_t)t * DD + fl];
        s_ch[tid]       = csum * inv;
        s_ch[256 + tid] = hp[(size_t)last * DD + fl];
    }
    __syncthreads();

    if (tid < 128) {
        float a = comb_b[tid];
        const float4* cw = (const float4*)(comb_w + (size_t)tid * 512);
        for (int k = 0; k < 128; ++k) {
            float4 w4 = cw[k];
            float4 v4 = *(const float4*)&s_ch[4 * k];
            a += w4.x * v4.x + w4.y * v4.y + w4.z * v4.z + w4.w * v4.w;
        }
        feat[(size_t)b * DD + tid] = tanhf(a);
    }
}

// ---------------------------------------------------------------------------
// K4b: logits = feat @ fc_w^T + fc_b   grid = B*4 = 128 blocks, 256 threads
// ---------------------------------------------------------------------------
__global__ __launch_bounds__(256) void k_logits(
    const float* __restrict__ feat, const float* __restrict__ fc_w,
    const float* __restrict__ fc_b, float* __restrict__ out)
{
    const int b   = blockIdx.x >> 2;
    const int oc  = blockIdx.x & 3;
    const int tid = threadIdx.x;
    const int o   = oc * 256 + tid;
    __shared__ __align__(16) float s_f[DD];
    if (tid < DD) s_f[tid] = feat[(size_t)b * DD + tid];
    __syncthreads();
    if (o < OUTN) {
        float a = fc_b[o];
        const float4* w4 = (const float4*)(fc_w + (size_t)o * DD);
        for (int k = 0; k < DD / 4; ++k) {
            float4 w = w4[k];
            float4 v = *(const float4*)&s_f[4 * k];
            a += w.x * v.x + w.y * v.y + w.z * v.z + w.w * v.w;
        }
        out[(size_t)b * OUTN + o] = a;
    }
}

// ---------------------------------------------------------------------------
extern "C" void kernel_launch(void* const* d_in, const int* in_sizes, int n_in,
                              void* d_out, int out_size, void* d_ws, size_t ws_size,
                              hipStream_t stream)
{
    const float* x      = (const float*)d_in[0];
    const float* emb    = (const float*)d_in[1];
    const float* wih_f  = (const float*)d_in[2];
    const float* whh_f  = (const float*)d_in[3];
    const float* bih_f  = (const float*)d_in[4];
    const float* bhh_f  = (const float*)d_in[5];
    const float* wih_b  = (const float*)d_in[6];
    const float* whh_b  = (const float*)d_in[7];
    const float* bih_b  = (const float*)d_in[8];
    const float* bhh_b  = (const float*)d_in[9];
    const float* attn_w = (const float*)d_in[10];
    const float* attn_b = (const float*)d_in[11];
    const float* comb_w = (const float*)d_in[12];
    const float* comb_b = (const float*)d_in[13];
    const float* fc_w   = (const float*)d_in[14];
    const float* fc_b   = (const float*)d_in[15];
    float* out = (float*)d_out;

    // workspace layout (floats)
    float* ws    = (float*)d_ws;
    float* e     = ws;                      // 409600
    float* x3    = ws + 409600;             // 2457600
    float* h_all = ws + 2867200;            // 819200
    float* feat  = ws + 3686400;            // 4096
    int*   mask  = (int*)(ws + 3690496);    // 3200      (total ~14.8 MB)

    k_embed  <<<BB * TT,     256, 0, stream>>>(x, emb, e, mask);
    k_gates  <<<(BB * TT)/8, 256, 0, stream>>>(e, wih_f, bih_f, wih_b, bih_b, x3);
    k_gru    <<<2 * BB,      512, 0, stream>>>(x3, whh_f, bhh_f, whh_b, bhh_b, h_all);
    k_attn   <<<BB,          256, 0, stream>>>(h_all, mask, attn_w, attn_b, comb_w, comb_b, feat);
    k_logits <<<BB * 4,      256, 0, stream>>>(feat, fc_w, fc_b, out);
}

// Round 12
// 350.688 us; speedup vs baseline: 2.6068x; 1.0085x over previous
//
#include <hip/hip_runtime.h>
#include <hip/hip_fp16.h>
#include <math.h>

#define BB 32
#define TT 100
#define VV 10000
#define DD 128
#define OUTN 1000
#define G3 384

// ---------------------------------------------------------------------------
// K0: one-shot weight conversion whh (f32) -> fp16. 49152 elems/dir, ~2us.
// Rationale: GRU step time = weight-stream bytes through the per-CU L1
// return path (~128B/cyc). fp32 stream floor 1536cyc/step (v7 measures 1786);
// fp16 halves bytes -> 768cyc floor. Weights ~N(0,0.05^2): fp16 rel err
// 4.9e-4 -> added logit error ~1e-4 (current absmax 2.4e-4).
// ---------------------------------------------------------------------------
__global__ __launch_bounds__(256) void k_w2h(
    const float* __restrict__ wf, const float* __restrict__ wb,
    __half* __restrict__ hf, __half* __restrict__ hb)
{
    const int i = blockIdx.x * 256 + threadIdx.x;   // grid covers 3*DD*DD
    hf[i] = __float2half(wf[i]);
    hb[i] = __float2half(wb[i]);
}

// ---------------------------------------------------------------------------
// K1: sparse embedding sum (unchanged R11)
// ---------------------------------------------------------------------------
__global__ __launch_bounds__(256) void k_embed(
    const float* __restrict__ x, const float* __restrict__ emb,
    float* __restrict__ e, int* __restrict__ mask)
{
    const int bt  = blockIdx.x;
    const int tid = threadIdx.x;
    __shared__ int   s_cnt;
    __shared__ int   s_any;
    __shared__ int   s_idx[256];
    __shared__ float s_val[256];
    if (tid == 0) { s_cnt = 0; s_any = 0; }
    __syncthreads();

    const float4* x4 = (const float4*)(x + (size_t)bt * VV);
    for (int i = tid; i < VV / 4; i += 256) {
        float4 v = x4[i];
        if (v.x != 0.f) { int p = atomicAdd(&s_cnt, 1); if (p < 256) { s_idx[p] = 4*i+0; s_val[p] = v.x; } }
        if (v.y != 0.f) { int p = atomicAdd(&s_cnt, 1); if (p < 256) { s_idx[p] = 4*i+1; s_val[p] = v.y; } }
        if (v.z != 0.f) { int p = atomicAdd(&s_cnt, 1); if (p < 256) { s_idx[p] = 4*i+2; s_val[p] = v.z; } }
        if (v.w != 0.f) { int p = atomicAdd(&s_cnt, 1); if (p < 256) { s_idx[p] = 4*i+3; s_val[p] = v.w; } }
    }
    __syncthreads();
    int cnt = s_cnt; if (cnt > 256) cnt = 256;
    if (tid < DD) {
        float a0 = 0.f, a1 = 0.f, a2 = 0.f, a3 = 0.f;
        int i = 0;
        for (; i + 3 < cnt; i += 4) {
            a0 += s_val[i+0] * emb[(size_t)s_idx[i+0] * DD + tid];
            a1 += s_val[i+1] * emb[(size_t)s_idx[i+1] * DD + tid];
            a2 += s_val[i+2] * emb[(size_t)s_idx[i+2] * DD + tid];
            a3 += s_val[i+3] * emb[(size_t)s_idx[i+3] * DD + tid];
        }
        for (; i < cnt; ++i)
            a0 += s_val[i] * emb[(size_t)s_idx[i] * DD + tid];
        float acc = (a0 + a1) + (a2 + a3);
        e[(size_t)bt * DD + tid] = acc;
        if (acc != 0.f) s_any = 1;
    }
    __syncthreads();
    if (tid == 0) mask[bt] = s_any;
}

// ---------------------------------------------------------------------------
// K2: input-side gates (unchanged R11)
// ---------------------------------------------------------------------------
__global__ __launch_bounds__(256) void k_gates(
    const float* __restrict__ e,
    const float* __restrict__ wih_f, const float* __restrict__ bih_f,
    const float* __restrict__ wih_b, const float* __restrict__ bih_b,
    float* __restrict__ x3)
{
    const int r0  = blockIdx.x * 8;
    const int tid = threadIdx.x;
    __shared__ __align__(16) float se[8][DD];
    for (int i = tid; i < 8 * DD; i += 256)
        se[i >> 7][i & 127] = e[(size_t)(r0 + (i >> 7)) * DD + (i & 127)];
    __syncthreads();

    for (int cc = 0; cc < 3; ++cc) {
        const int col = tid + cc * 256;
        const float* wrow;
        float bias;
        if (col < G3) { wrow = wih_f + (size_t)col * DD;        bias = bih_f[col]; }
        else          { wrow = wih_b + (size_t)(col - G3) * DD; bias = bih_b[col - G3]; }
        float acc[8];
        #pragma unroll
        for (int r = 0; r < 8; ++r) acc[r] = 0.f;
        const float4* w4 = (const float4*)wrow;
        for (int k4 = 0; k4 < DD / 4; ++k4) {
            float4 w = w4[k4];
            #pragma unroll
            for (int r = 0; r < 8; ++r) {
                float4 ev = *(const float4*)&se[r][4 * k4];
                acc[r] += ev.x * w.x + ev.y * w.y + ev.z * w.z + ev.w * w.w;
            }
        }
        #pragma unroll
        for (int r = 0; r < 8; ++r)
            x3[(size_t)(r0 + r) * 768 + col] = acc[r] + bias;
    }
}

// ---------------------------------------------------------------------------
// asm global load (asm-defined => not rematerializable)
// ---------------------------------------------------------------------------
__device__ __forceinline__ uint4 ld_pin_u128(const uint4* p)
{
    uint4 r;
    asm volatile("global_load_dwordx4 %0, %1, off" : "=v"(r) : "v"(p));
    return r;
}

__device__ __forceinline__ float2 h2f2(unsigned u)
{
    __half2 h = *reinterpret_cast<__half2*>(&u);
    return __half22float2(h);
}

// ---------------------------------------------------------------------------
// K3: GRU v11 — fp16 weight stream (halved bytes). 512 thr = (g x kq), 64 blk.
// v1-v10 verdict: 96 fp32 weight floats/thread cannot be made resident
// (every mechanism spilled/remat'd). fp16 halves both the stream (98KB/step,
// 768cyc floor) AND the register footprint (48 VGPR) — robust either way:
// resident -> step ~= max(DS 770, VALU ~890 incl 96 cvt); streamed -> 768cyc
// stream overlapping VALU. Both ~1100cyc vs v7's 1786. h stays fp32 (only
// weights quantized). Falsifier: accuracy fail => revert R11, ROOFLINE.
// ---------------------------------------------------------------------------
__global__ __launch_bounds__(512, 1) void k_gru(
    const float* __restrict__ x3,
    const __half* __restrict__ whh16_f, const float* __restrict__ bhh_f,
    const __half* __restrict__ whh16_b, const float* __restrict__ bhh_b,
    float* __restrict__ h_all)
{
    const int dir = blockIdx.x & 1;
    const int b   = blockIdx.x >> 1;
    const int tid = threadIdx.x;       // 0..511
    const int g   = tid & 127;         // output dim
    const int kq  = tid >> 7;          // k-quarter: 0..3
    const int kb  = kq * 32;           // k base
    const __half* whh = dir ? whh16_b : whh16_f;
    const float*  bhh = dir ? bhh_b  : bhh_f;

    // each gate row: 32 halves = 64B = 2 uint4 loads... 32 halves = 4 words x2
    const uint4* pr4 = (const uint4*)(whh + (size_t)(g         ) * DD + kb);
    const uint4* pz4 = (const uint4*)(whh + (size_t)(DD     + g) * DD + kb);
    const uint4* pn4 = (const uint4*)(whh + (size_t)(2 * DD + g) * DD + kb);

#define Q4(M) M(0) M(1) M(2) M(3)
    // 12 uint4 = 96 halves (48 VGPRs)
#define DECLW(j) uint4 wr##j = ld_pin_u128(pr4 + (j)); \
                 uint4 wz##j = ld_pin_u128(pz4 + (j)); \
                 uint4 wn##j = ld_pin_u128(pn4 + (j));
    // NOTE: each uint4 j covers 8 k-values [8j..8j+7]; 4 of them = 32 k's
    Q4(DECLW)
#undef DECLW
    asm volatile("s_waitcnt vmcnt(0)" ::: "memory");
    __builtin_amdgcn_sched_barrier(0);

    float bhr = 0.f, bhz = 0.f, bhn = 0.f;
    if (tid < DD) { bhr = bhh[g]; bhz = bhh[DD + g]; bhn = bhh[2 * DD + g]; }

    __shared__ __align__(16) float h_lds[DD];
    __shared__ float p_lds[9 * DD];    // [(kq-1)*3 + gate][g]
    float h_reg = 0.f;
    if (tid < DD) h_lds[tid] = 0.f;

    // prefetch x3 for t=0
    float xr = 0.f, xz = 0.f, xn = 0.f;
    {
        const float* x3p = x3 + (size_t)(b * TT + (dir ? TT - 1 : 0)) * 768 + dir * G3;
        if (tid < DD) { xr = x3p[g]; xz = x3p[DD + g]; xn = x3p[2 * DD + g]; }
    }
    __syncthreads();

    for (int t = 0; t < TT; ++t) {
        const int te = dir ? (TT - 1 - t) : t;

        // prefetch x3 for t+1 (hidden under this step's dot + barriers)
        float nxr = 0.f, nxz = 0.f, nxn = 0.f;
        if (t + 1 < TT) {
            const int tn = dir ? (TT - 2 - t) : (t + 1);
            const float* x3n = x3 + (size_t)(b * TT + tn) * 768 + dir * G3;
            if (tid < DD) { nxr = x3n[g]; nxz = x3n[DD + g]; nxn = x3n[2 * DD + g]; }
        }

        // partial dots over this thread's k-quarter; 6 independent chains.
        // per chunk j: 8 k's; per gate 4 words -> 2 cvt + 2 FMA each.
        float ar0 = 0.f, ar1 = 0.f, az0 = 0.f, az1 = 0.f, an0 = 0.f, an1 = 0.f;
#define FMA8(j) { \
        const float4 ha = *(const float4*)&h_lds[kb + 8 * (j)]; \
        const float4 hc = *(const float4*)&h_lds[kb + 8 * (j) + 4]; \
        float2 f; \
        f = h2f2(wr##j.x); ar0 += f.x*ha.x + f.y*ha.y; \
        f = h2f2(wr##j.y); ar1 += f.x*ha.z + f.y*ha.w; \
        f = h2f2(wr##j.z); ar0 += f.x*hc.x + f.y*hc.y; \
        f = h2f2(wr##j.w); ar1 += f.x*hc.z + f.y*hc.w; \
        f = h2f2(wz##j.x); az0 += f.x*ha.x + f.y*ha.y; \
        f = h2f2(wz##j.y); az1 += f.x*ha.z + f.y*ha.w; \
        f = h2f2(wz##j.z); az0 += f.x*hc.x + f.y*hc.y; \
        f = h2f2(wz##j.w); az1 += f.x*hc.z + f.y*hc.w; \
        f = h2f2(wn##j.x); an0 += f.x*ha.x + f.y*ha.y; \
        f = h2f2(wn##j.y); an1 += f.x*ha.z + f.y*ha.w; \
        f = h2f2(wn##j.z); an0 += f.x*hc.x + f.y*hc.y; \
        f = h2f2(wn##j.w); an1 += f.x*hc.z + f.y*hc.w; }
        Q4(FMA8)
#undef FMA8
        const float pr = ar0 + ar1, pz = az0 + az1, pn = an0 + an1;

        if (kq) {
            const int q = (kq - 1) * 3;
            p_lds[(q + 0) * DD + g] = pr;
            p_lds[(q + 1) * DD + g] = pz;
            p_lds[(q + 2) * DD + g] = pn;
        }
        __syncthreads();

        if (tid < DD) {
            float hr = pr + p_lds[0*DD+g] + p_lds[3*DD+g] + p_lds[6*DD+g] + bhr;
            float hz = pz + p_lds[1*DD+g] + p_lds[4*DD+g] + p_lds[7*DD+g] + bhz;
            float hn = pn + p_lds[2*DD+g] + p_lds[5*DD+g] + p_lds[8*DD+g] + bhn;
            float r  = __builtin_amdgcn_rcpf(1.f + __expf(-(xr + hr)));
            float z  = __builtin_amdgcn_rcpf(1.f + __expf(-(xz + hz)));
            // tanh(x) = 1 - 2/(e^(2x)+1): safe at +/-inf
            float e2 = __expf(2.f * (xn + r * hn));
            float n  = 1.f - 2.f * __builtin_amdgcn_rcpf(e2 + 1.f);
            float hnew = n + z * (h_reg - n);            // == (1-z)*n + z*h
            h_reg = hnew;
            h_lds[g] = hnew;
            h_all[(size_t)((dir * BB + b) * TT + te) * DD + g] = hnew;
        }
        __syncthreads();
        xr = nxr; xz = nxz; xn = nxn;
    }
#undef Q4
}

// ---------------------------------------------------------------------------
// K4a: per-batch attention + h_last + combine -> feat[b,128] (unchanged R11)
// ---------------------------------------------------------------------------
__global__ __launch_bounds__(256) void k_attn(
    const float* __restrict__ h_all, const int* __restrict__ mask,
    const float* __restrict__ attn_w, const float* __restrict__ attn_b,
    const float* __restrict__ comb_w, const float* __restrict__ comb_b,
    float* __restrict__ feat)
{
    const int b   = blockIdx.x;
    const int tid = threadIdx.x;
    __shared__ float s_aw[256];
    __shared__ float s_sc[128];
    __shared__ int   s_m[128];
    __shared__ float s_red[128];
    __shared__ __align__(16) float s_ch[512];

    s_aw[tid] = attn_w[tid];
    int m = 0;
    if (tid < 128) {
        m = (tid < TT) ? mask[b * TT + tid] : 0;
        s_m[tid] = m;
    }
    __syncthreads();
    for (int s = 64; s > 0; s >>= 1) {
        if (tid < s) s_m[tid] += s_m[tid + s];
        __syncthreads();
    }
    const int last = s_m[0] - 1;

    const float* hf = h_all + (size_t)(0 * BB + b) * TT * DD;
    const float* hb = h_all + (size_t)(1 * BB + b) * TT * DD;

    float sc = -1e9f;
    if (tid < TT) {
        float a = attn_b[0];
        const float4* hf4 = (const float4*)(hf + (size_t)tid * DD);
        const float4* hb4 = (const float4*)(hb + (size_t)tid * DD);
        for (int k = 0; k < DD / 4; ++k) {
            float4 v = hf4[k];
            a += v.x * s_aw[4*k] + v.y * s_aw[4*k+1] + v.z * s_aw[4*k+2] + v.w * s_aw[4*k+3];
        }
        for (int k = 0; k < DD / 4; ++k) {
            float4 v = hb4[k];
            a += v.x * s_aw[DD+4*k] + v.y * s_aw[DD+4*k+1] + v.z * s_aw[DD+4*k+2] + v.w * s_aw[DD+4*k+3];
        }
        sc = m ? a : -1e9f;
    }
    if (tid < 128) { s_sc[tid] = sc; s_red[tid] = sc; }
    __syncthreads();
    for (int s = 64; s > 0; s >>= 1) {
        if (tid < s) s_red[tid] = fmaxf(s_red[tid], s_red[tid + s]);
        __syncthreads();
    }
    const float mx = s_red[0];
    __syncthreads();
    float ex = 0.f;
    if (tid < 128) { ex = __expf(s_sc[tid] - mx); s_sc[tid] = ex; s_red[tid] = ex; }
    __syncthreads();
    for (int s = 64; s > 0; s >>= 1) {
        if (tid < s) s_red[tid] += s_red[tid + s];
        __syncthreads();
    }
    const float inv = 1.f / s_red[0];
    __syncthreads();

    {
        const int fl = tid & 127;
        const float* hp = (tid < 128) ? hf : hb;
        float csum = 0.f;
        for (int t = 0; t < TT; ++t)
            csum += s_sc[t] * hp[(size_t)t * DD + fl];
        s_ch[tid]       = csum * inv;
        s_ch[256 + tid] = hp[(size_t)last * DD + fl];
    }
    __syncthreads();

    if (tid < 128) {
        float a = comb_b[tid];
        const float4* cw = (const float4*)(comb_w + (size_t)tid * 512);
        for (int k = 0; k < 128; ++k) {
            float4 w4 = cw[k];
            float4 v4 = *(const float4*)&s_ch[4 * k];
            a += w4.x * v4.x + w4.y * v4.y + w4.z * v4.z + w4.w * v4.w;
        }
        feat[(size_t)b * DD + tid] = tanhf(a);
    }
}

// ---------------------------------------------------------------------------
// K4b: logits (unchanged R11)
// ---------------------------------------------------------------------------
__global__ __launch_bounds__(256) void k_logits(
    const float* __restrict__ feat, const float* __restrict__ fc_w,
    const float* __restrict__ fc_b, float* __restrict__ out)
{
    const int b   = blockIdx.x >> 2;
    const int oc  = blockIdx.x & 3;
    const int tid = threadIdx.x;
    const int o   = oc * 256 + tid;
    __shared__ __align__(16) float s_f[DD];
    if (tid < DD) s_f[tid] = feat[(size_t)b * DD + tid];
    __syncthreads();
    if (o < OUTN) {
        float a = fc_b[o];
        const float4* w4 = (const float4*)(fc_w + (size_t)o * DD);
        for (int k = 0; k < DD / 4; ++k) {
            float4 w = w4[k];
            float4 v = *(const float4*)&s_f[4 * k];
            a += w.x * v.x + w.y * v.y + w.z * v.z + w.w * v.w;
        }
        out[(size_t)b * OUTN + o] = a;
    }
}

// ---------------------------------------------------------------------------
extern "C" void kernel_launch(void* const* d_in, const int* in_sizes, int n_in,
                              void* d_out, int out_size, void* d_ws, size_t ws_size,
                              hipStream_t stream)
{
    const float* x      = (const float*)d_in[0];
    const float* emb    = (const float*)d_in[1];
    const float* wih_f  = (const float*)d_in[2];
    const float* whh_f  = (const float*)d_in[3];
    const float* bih_f  = (const float*)d_in[4];
    const float* bhh_f  = (const float*)d_in[5];
    const float* wih_b  = (const float*)d_in[6];
    const float* whh_b  = (const float*)d_in[7];
    const float* bih_b  = (const float*)d_in[8];
    const float* bhh_b  = (const float*)d_in[9];
    const float* attn_w = (const float*)d_in[10];
    const float* attn_b = (const float*)d_in[11];
    const float* comb_w = (const float*)d_in[12];
    const float* comb_b = (const float*)d_in[13];
    const float* fc_w   = (const float*)d_in[14];
    const float* fc_b   = (const float*)d_in[15];
    float* out = (float*)d_out;

    // workspace layout (floats)
    float*  ws      = (float*)d_ws;
    float*  e       = ws;                       // 409600
    float*  x3      = ws + 409600;              // 2457600
    float*  h_all   = ws + 2867200;             // 819200
    float*  feat    = ws + 3686400;             // 4096
    int*    mask    = (int*)(ws + 3690496);     // 3200
    __half* whh16_f = (__half*)(ws + 3693696);  // 49152 halves = 24576 floats
    __half* whh16_b = (__half*)(ws + 3718272);  // 49152 halves (total ~15 MB)

    k_w2h    <<<(3*DD*DD)/256, 256, 0, stream>>>(whh_f, whh_b, whh16_f, whh16_b);
    k_embed  <<<BB * TT,     256, 0, stream>>>(x, emb, e, mask);
    k_gates  <<<(BB * TT)/8, 256, 0, stream>>>(e, wih_f, bih_f, wih_b, bih_b, x3);
    k_gru    <<<2 * BB,      512, 0, stream>>>(x3, whh16_f, bhh_f, whh16_b, bhh_b, h_all);
    k_attn   <<<BB,          256, 0, stream>>>(h_all, mask, attn_w, attn_b, comb_w, comb_b, feat);
    k_logits <<<BB * 4,      256, 0, stream>>>(feat, fc_w, fc_b, out);
}

// Round 13
// 338.567 us; speedup vs baseline: 2.7001x; 1.0358x over previous
//
#include <hip/hip_runtime.h>
#include <hip/hip_fp16.h>
#include <math.h>

#define BB 32
#define TT 100
#define VV 10000
#define DD 128
#define OUTN 1000
#define G3 384

// ---------------------------------------------------------------------------
// K0: one-shot weight conversion whh (f32) -> fp16 (unchanged R12)
// ---------------------------------------------------------------------------
__global__ __launch_bounds__(256) void k_w2h(
    const float* __restrict__ wf, const float* __restrict__ wb,
    __half* __restrict__ hf, __half* __restrict__ hb)
{
    const int i = blockIdx.x * 256 + threadIdx.x;   // grid covers 3*DD*DD
    hf[i] = __float2half(wf[i]);
    hb[i] = __float2half(wb[i]);
}

// ---------------------------------------------------------------------------
// K1: sparse embedding sum (unchanged)
// ---------------------------------------------------------------------------
__global__ __launch_bounds__(256) void k_embed(
    const float* __restrict__ x, const float* __restrict__ emb,
    float* __restrict__ e, int* __restrict__ mask)
{
    const int bt  = blockIdx.x;
    const int tid = threadIdx.x;
    __shared__ int   s_cnt;
    __shared__ int   s_any;
    __shared__ int   s_idx[256];
    __shared__ float s_val[256];
    if (tid == 0) { s_cnt = 0; s_any = 0; }
    __syncthreads();

    const float4* x4 = (const float4*)(x + (size_t)bt * VV);
    for (int i = tid; i < VV / 4; i += 256) {
        float4 v = x4[i];
        if (v.x != 0.f) { int p = atomicAdd(&s_cnt, 1); if (p < 256) { s_idx[p] = 4*i+0; s_val[p] = v.x; } }
        if (v.y != 0.f) { int p = atomicAdd(&s_cnt, 1); if (p < 256) { s_idx[p] = 4*i+1; s_val[p] = v.y; } }
        if (v.z != 0.f) { int p = atomicAdd(&s_cnt, 1); if (p < 256) { s_idx[p] = 4*i+2; s_val[p] = v.z; } }
        if (v.w != 0.f) { int p = atomicAdd(&s_cnt, 1); if (p < 256) { s_idx[p] = 4*i+3; s_val[p] = v.w; } }
    }
    __syncthreads();
    int cnt = s_cnt; if (cnt > 256) cnt = 256;
    if (tid < DD) {
        float a0 = 0.f, a1 = 0.f, a2 = 0.f, a3 = 0.f;
        int i = 0;
        for (; i + 3 < cnt; i += 4) {
            a0 += s_val[i+0] * emb[(size_t)s_idx[i+0] * DD + tid];
            a1 += s_val[i+1] * emb[(size_t)s_idx[i+1] * DD + tid];
            a2 += s_val[i+2] * emb[(size_t)s_idx[i+2] * DD + tid];
            a3 += s_val[i+3] * emb[(size_t)s_idx[i+3] * DD + tid];
        }
        for (; i < cnt; ++i)
            a0 += s_val[i] * emb[(size_t)s_idx[i] * DD + tid];
        float acc = (a0 + a1) + (a2 + a3);
        e[(size_t)bt * DD + tid] = acc;
        if (acc != 0.f) s_any = 1;
    }
    __syncthreads();
    if (tid == 0) mask[bt] = s_any;
}

// ---------------------------------------------------------------------------
// K2: input-side gates (unchanged)
// ---------------------------------------------------------------------------
__global__ __launch_bounds__(256) void k_gates(
    const float* __restrict__ e,
    const float* __restrict__ wih_f, const float* __restrict__ bih_f,
    const float* __restrict__ wih_b, const float* __restrict__ bih_b,
    float* __restrict__ x3)
{
    const int r0  = blockIdx.x * 8;
    const int tid = threadIdx.x;
    __shared__ __align__(16) float se[8][DD];
    for (int i = tid; i < 8 * DD; i += 256)
        se[i >> 7][i & 127] = e[(size_t)(r0 + (i >> 7)) * DD + (i & 127)];
    __syncthreads();

    for (int cc = 0; cc < 3; ++cc) {
        const int col = tid + cc * 256;
        const float* wrow;
        float bias;
        if (col < G3) { wrow = wih_f + (size_t)col * DD;        bias = bih_f[col]; }
        else          { wrow = wih_b + (size_t)(col - G3) * DD; bias = bih_b[col - G3]; }
        float acc[8];
        #pragma unroll
        for (int r = 0; r < 8; ++r) acc[r] = 0.f;
        const float4* w4 = (const float4*)wrow;
        for (int k4 = 0; k4 < DD / 4; ++k4) {
            float4 w = w4[k4];
            #pragma unroll
            for (int r = 0; r < 8; ++r) {
                float4 ev = *(const float4*)&se[r][4 * k4];
                acc[r] += ev.x * w.x + ev.y * w.y + ev.z * w.z + ev.w * w.w;
            }
        }
        #pragma unroll
        for (int r = 0; r < 8; ++r)
            x3[(size_t)(r0 + r) * 768 + col] = acc[r] + bias;
    }
}

// ---------------------------------------------------------------------------
// asm global load (asm-defined => not rematerializable)
// ---------------------------------------------------------------------------
__device__ __forceinline__ uint4 ld_pin_u128(const uint4* p)
{
    uint4 r;
    asm volatile("global_load_dwordx4 %0, %1, off" : "=v"(r) : "v"(p));
    return r;
}

typedef _Float16 h2v __attribute__((ext_vector_type(2)));
__device__ __forceinline__ h2v u2h2(unsigned u) { h2v h; __builtin_memcpy(&h, &u, 4); return h; }
__device__ __forceinline__ float2 h2f2(unsigned u)
{
    __half2 h = *reinterpret_cast<__half2*>(&u);
    return __half22float2(h);
}

#if __has_builtin(__builtin_amdgcn_fdot2)
#define DOT2(acc, wu, hu) acc = __builtin_amdgcn_fdot2(u2h2(wu), u2h2(hu), acc, false);
#else
#define DOT2(acc, wu, hu) { float2 wf_ = h2f2(wu); float2 hf_ = h2f2(hu); acc += wf_.x*hf_.x + wf_.y*hf_.y; }
#endif

// ---------------------------------------------------------------------------
// K3: GRU v12 — fp16 h-BROADCAST + dot2.
// R12 post-mortem: halving weight-stream bytes gave only -3us => GRU is NOT
// byte-bound; it is DS-broadcast + barrier bound. The broadcast read count
// (waves x k_per_thread/4 = 64 ds_read_b128/step, ~770cyc) is invariant
// under thread-split — the ONLY lever is bytes per h element. v12 stores the
// broadcast copy of h as fp16: one b128 carries 8 h values -> 32 reads/step
// (~384cyc). v_dot2_f32_f16 (fp32 accum) does 2 MACs/instr: 48 dot2/thread
// (~240cyc VALU). Step ~= 384 DS || 240 VALU + ~400 barrier/tail ~= 850cyc
// vs R12's ~1650. h recurrence stays fp32 (h_reg); only the broadcast copy
// is quantized. Falsifier A: accuracy fail -> revert R12 + ROOFLINE.
// Falsifier B: total moves <8us -> decomposition wrong -> ROOFLINE.
// ---------------------------------------------------------------------------
__global__ __launch_bounds__(512, 1) void k_gru(
    const float* __restrict__ x3,
    const __half* __restrict__ whh16_f, const float* __restrict__ bhh_f,
    const __half* __restrict__ whh16_b, const float* __restrict__ bhh_b,
    float* __restrict__ h_all)
{
    const int dir = blockIdx.x & 1;
    const int b   = blockIdx.x >> 1;
    const int tid = threadIdx.x;       // 0..511
    const int g   = tid & 127;         // output dim
    const int kq  = tid >> 7;          // k-quarter: 0..3
    const int kb  = kq * 32;           // k base (elements)
    const __half* whh = dir ? whh16_b : whh16_f;
    const float*  bhh = dir ? bhh_b  : bhh_f;

    const uint4* pr4 = (const uint4*)(whh + (size_t)(g         ) * DD + kb);
    const uint4* pz4 = (const uint4*)(whh + (size_t)(DD     + g) * DD + kb);
    const uint4* pn4 = (const uint4*)(whh + (size_t)(2 * DD + g) * DD + kb);

#define Q4(M) M(0) M(1) M(2) M(3)
    // 12 uint4 = 96 halves (48 VGPRs)
#define DECLW(j) uint4 wr##j = ld_pin_u128(pr4 + (j)); \
                 uint4 wz##j = ld_pin_u128(pz4 + (j)); \
                 uint4 wn##j = ld_pin_u128(pn4 + (j));
    Q4(DECLW)
#undef DECLW
    asm volatile("s_waitcnt vmcnt(0)" ::: "memory");
    __builtin_amdgcn_sched_barrier(0);

    float bhr = 0.f, bhz = 0.f, bhn = 0.f;
    if (tid < DD) { bhr = bhh[g]; bhz = bhh[DD + g]; bhn = bhh[2 * DD + g]; }

    __shared__ __align__(16) __half h16[DD];   // fp16 broadcast copy of h
    __shared__ float p_lds[9 * DD];            // [(kq-1)*3 + gate][g]
    float h_reg = 0.f;
    if (tid < DD) h16[tid] = __float2half(0.f);

    // prefetch x3 for t=0
    float xr = 0.f, xz = 0.f, xn = 0.f;
    {
        const float* x3p = x3 + (size_t)(b * TT + (dir ? TT - 1 : 0)) * 768 + dir * G3;
        if (tid < DD) { xr = x3p[g]; xz = x3p[DD + g]; xn = x3p[2 * DD + g]; }
    }
    __syncthreads();

    for (int t = 0; t < TT; ++t) {
        const int te = dir ? (TT - 1 - t) : t;

        // prefetch x3 for t+1 (hidden under this step's dot + barriers)
        float nxr = 0.f, nxz = 0.f, nxn = 0.f;
        if (t + 1 < TT) {
            const int tn = dir ? (TT - 2 - t) : (t + 1);
            const float* x3n = x3 + (size_t)(b * TT + tn) * 768 + dir * G3;
            if (tid < DD) { nxr = x3n[g]; nxz = x3n[DD + g]; nxn = x3n[2 * DD + g]; }
        }

        // partial dots over this thread's k-quarter; one b128 = 8 h values
        float ar0 = 0.f, ar1 = 0.f, az0 = 0.f, az1 = 0.f, an0 = 0.f, an1 = 0.f;
#define FMA8(j) { \
        const uint4 hv = *(const uint4*)&h16[kb + 8 * (j)]; \
        DOT2(ar0, wr##j.x, hv.x) DOT2(ar1, wr##j.y, hv.y) \
        DOT2(ar0, wr##j.z, hv.z) DOT2(ar1, wr##j.w, hv.w) \
        DOT2(az0, wz##j.x, hv.x) DOT2(az1, wz##j.y, hv.y) \
        DOT2(az0, wz##j.z, hv.z) DOT2(az1, wz##j.w, hv.w) \
        DOT2(an0, wn##j.x, hv.x) DOT2(an1, wn##j.y, hv.y) \
        DOT2(an0, wn##j.z, hv.z) DOT2(an1, wn##j.w, hv.w) }
        Q4(FMA8)
#undef FMA8
        const float pr = ar0 + ar1, pz = az0 + az1, pn = an0 + an1;

        if (kq) {
            const int q = (kq - 1) * 3;
            p_lds[(q + 0) * DD + g] = pr;
            p_lds[(q + 1) * DD + g] = pz;
            p_lds[(q + 2) * DD + g] = pn;
        }
        __syncthreads();

        if (tid < DD) {
            float hr = pr + p_lds[0*DD+g] + p_lds[3*DD+g] + p_lds[6*DD+g] + bhr;
            float hz = pz + p_lds[1*DD+g] + p_lds[4*DD+g] + p_lds[7*DD+g] + bhz;
            float hn = pn + p_lds[2*DD+g] + p_lds[5*DD+g] + p_lds[8*DD+g] + bhn;
            float r  = __builtin_amdgcn_rcpf(1.f + __expf(-(xr + hr)));
            float z  = __builtin_amdgcn_rcpf(1.f + __expf(-(xz + hz)));
            // tanh(x) = 1 - 2/(e^(2x)+1): safe at +/-inf
            float e2 = __expf(2.f * (xn + r * hn));
            float n  = 1.f - 2.f * __builtin_amdgcn_rcpf(e2 + 1.f);
            float hnew = n + z * (h_reg - n);            // == (1-z)*n + z*h
            h_reg = hnew;
            h16[g] = __float2half(hnew);
            h_all[(size_t)((dir * BB + b) * TT + te) * DD + g] = hnew;
        }
        __syncthreads();
        xr = nxr; xz = nxz; xn = nxn;
    }
#undef Q4
}

// ---------------------------------------------------------------------------
// K4a: per-batch attention + h_last + combine -> feat[b,128] (unchanged)
// ---------------------------------------------------------------------------
__global__ __launch_bounds__(256) void k_attn(
    const float* __restrict__ h_all, const int* __restrict__ mask,
    const float* __restrict__ attn_w, const float* __restrict__ attn_b,
    const float* __restrict__ comb_w, const float* __restrict__ comb_b,
    float* __restrict__ feat)
{
    const int b   = blockIdx.x;
    const int tid = threadIdx.x;
    __shared__ float s_aw[256];
    __shared__ float s_sc[128];
    __shared__ int   s_m[128];
    __shared__ float s_red[128];
    __shared__ __align__(16) float s_ch[512];

    s_aw[tid] = attn_w[tid];
    int m = 0;
    if (tid < 128) {
        m = (tid < TT) ? mask[b * TT + tid] : 0;
        s_m[tid] = m;
    }
    __syncthreads();
    for (int s = 64; s > 0; s >>= 1) {
        if (tid < s) s_m[tid] += s_m[tid + s];
        __syncthreads();
    }
    const int last = s_m[0] - 1;

    const float* hf = h_all + (size_t)(0 * BB + b) * TT * DD;
    const float* hb = h_all + (size_t)(1 * BB + b) * TT * DD;

    float sc = -1e9f;
    if (tid < TT) {
        float a = attn_b[0];
        const float4* hf4 = (const float4*)(hf + (size_t)tid * DD);
        const float4* hb4 = (const float4*)(hb + (size_t)tid * DD);
        for (int k = 0; k < DD / 4; ++k) {
            float4 v = hf4[k];
            a += v.x * s_aw[4*k] + v.y * s_aw[4*k+1] + v.z * s_aw[4*k+2] + v.w * s_aw[4*k+3];
        }
        for (int k = 0; k < DD / 4; ++k) {
            float4 v = hb4[k];
            a += v.x * s_aw[DD+4*k] + v.y * s_aw[DD+4*k+1] + v.z * s_aw[DD+4*k+2] + v.w * s_aw[DD+4*k+3];
        }
        sc = m ? a : -1e9f;
    }
    if (tid < 128) { s_sc[tid] = sc; s_red[tid] = sc; }
    __syncthreads();
    for (int s = 64; s > 0; s >>= 1) {
        if (tid < s) s_red[tid] = fmaxf(s_red[tid], s_red[tid + s]);
        __syncthreads();
    }
    const float mx = s_red[0];
    __syncthreads();
    float ex = 0.f;
    if (tid < 128) { ex = __expf(s_sc[tid] - mx); s_sc[tid] = ex; s_red[tid] = ex; }
    __syncthreads();
    for (int s = 64; s > 0; s >>= 1) {
        if (tid < s) s_red[tid] += s_red[tid + s];
        __syncthreads();
    }
    const float inv = 1.f / s_red[0];
    __syncthreads();

    {
        const int fl = tid & 127;
        const float* hp = (tid < 128) ? hf : hb;
        float csum = 0.f;
        for (int t = 0; t < TT; ++t)
            csum += s_sc[t] * hp[(size_t)t * DD + fl];
        s_ch[tid]       = csum * inv;
        s_ch[256 + tid] = hp[(size_t)last * DD + fl];
    }
    __syncthreads();

    if (tid < 128) {
        float a = comb_b[tid];
        const float4* cw = (const float4*)(comb_w + (size_t)tid * 512);
        for (int k = 0; k < 128; ++k) {
            float4 w4 = cw[k];
            float4 v4 = *(const float4*)&s_ch[4 * k];
            a += w4.x * v4.x + w4.y * v4.y + w4.z * v4.z + w4.w * v4.w;
        }
        feat[(size_t)b * DD + tid] = tanhf(a);
    }
}

// ---------------------------------------------------------------------------
// K4b: logits (unchanged)
// ---------------------------------------------------------------------------
__global__ __launch_bounds__(256) void k_logits(
    const float* __restrict__ feat, const float* __restrict__ fc_w,
    const float* __restrict__ fc_b, float* __restrict__ out)
{
    const int b   = blockIdx.x >> 2;
    const int oc  = blockIdx.x & 3;
    const int tid = threadIdx.x;
    const int o   = oc * 256 + tid;
    __shared__ __align__(16) float s_f[DD];
    if (tid < DD) s_f[tid] = feat[(size_t)b * DD + tid];
    __syncthreads();
    if (o < OUTN) {
        float a = fc_b[o];
        const float4* w4 = (const float4*)(fc_w + (size_t)o * DD);
        for (int k = 0; k < DD / 4; ++k) {
            float4 w = w4[k];
            float4 v = *(const float4*)&s_f[4 * k];
            a += w.x * v.x + w.y * v.y + w.z * v.z + w.w * v.w;
        }
        out[(size_t)b * OUTN + o] = a;
    }
}

// ---------------------------------------------------------------------------
extern "C" void kernel_launch(void* const* d_in, const int* in_sizes, int n_in,
                              void* d_out, int out_size, void* d_ws, size_t ws_size,
                              hipStream_t stream)
{
    const float* x      = (const float*)d_in[0];
    const float* emb    = (const float*)d_in[1];
    const float* wih_f  = (const float*)d_in[2];
    const float* whh_f  = (const float*)d_in[3];
    const float* bih_f  = (const float*)d_in[4];
    const float* bhh_f  = (const float*)d_in[5];
    const float* wih_b  = (const float*)d_in[6];
    const float* whh_b  = (const float*)d_in[7];
    const float* bih_b  = (const float*)d_in[8];
    const float* bhh_b  = (const float*)d_in[9];
    const float* attn_w = (const float*)d_in[10];
    const float* attn_b = (const float*)d_in[11];
    const float* comb_w = (const float*)d_in[12];
    const float* comb_b = (const float*)d_in[13];
    const float* fc_w   = (const float*)d_in[14];
    const float* fc_b   = (const float*)d_in[15];
    float* out = (float*)d_out;

    // workspace layout (floats)
    float*  ws      = (float*)d_ws;
    float*  e       = ws;                       // 409600
    float*  x3      = ws + 409600;              // 2457600
    float*  h_all   = ws + 2867200;             // 819200
    float*  feat    = ws + 3686400;             // 4096
    int*    mask    = (int*)(ws + 3690496);     // 3200
    __half* whh16_f = (__half*)(ws + 3693696);  // 49152 halves = 24576 floats
    __half* whh16_b = (__half*)(ws + 3718272);  // 49152 halves (total ~15 MB)

    k_w2h    <<<(3*DD*DD)/256, 256, 0, stream>>>(whh_f, whh_b, whh16_f, whh16_b);
    k_embed  <<<BB * TT,     256, 0, stream>>>(x, emb, e, mask);
    k_gates  <<<(BB * TT)/8, 256, 0, stream>>>(e, wih_f, bih_f, wih_b, bih_b, x3);
    k_gru    <<<2 * BB,      512, 0, stream>>>(x3, whh16_f, bhh_f, whh16_b, bhh_b, h_all);
    k_attn   <<<BB,          256, 0, stream>>>(h_all, mask, attn_w, attn_b, comb_w, comb_b, feat);
    k_logits <<<BB * 4,      256, 0, stream>>>(feat, fc_w, fc_b, out);
}